// Round 5
// baseline (2101.288 us; speedup 1.0000x reference)
//
#include <hip/hip_runtime.h>
#include <hip/hip_bf16.h>
#include <math.h>

typedef __hip_bfloat16 bf16;
typedef __attribute__((ext_vector_type(8))) short bf16x8;
typedef __attribute__((ext_vector_type(4))) float f32x4;

#define DEPTH  4
#define HEADS  16
#define DIM    1024
#define DHEAD  64
#define MLPD   4096
#define BB     4
#define NN     1024
#define MMK    1024
#define ROWS   (BB*NN)     // 4096 token rows

__device__ inline float bitsbf(short s) {
  union { float f; unsigned u; } c; c.u = ((unsigned)(unsigned short)s) << 16; return c.f;
}
__device__ inline short bfbits(float f) {
  bf16 h = __float2bfloat16(f); return *(short*)&h;
}

// async global->LDS 16B per lane. LDS dest = wave-uniform base + lane*16B.
__device__ inline void gload_lds16(const bf16* g, bf16* l) {
  __builtin_amdgcn_global_load_lds((const __attribute__((address_space(1))) unsigned int*)g,
                                   (__attribute__((address_space(3))) unsigned int*)l, 16, 0, 0);
}

// ---------------- f32 -> bf16 convert ----------------
__global__ __launch_bounds__(256) void f2b_kernel(const float* __restrict__ in, bf16* __restrict__ out, int n) {
  int i = blockIdx.x * 256 + threadIdx.x;
  if (i < n) out[i] = __float2bfloat16(in[i]);
}

// ---------------- generalized transpose + f32->bf16 ----------------
// out[n][k] = bf16( in[(rowOff + k) * inStride + colOff + n] )
__global__ __launch_bounds__(256) void transpose_f2b(const float* __restrict__ in, bf16* __restrict__ out,
                                                     int inStride, int rowOff, int colOff, int outStride) {
  __shared__ float tile[32][33];
  int n0 = blockIdx.x * 32, k0 = blockIdx.y * 32;
  int tx = threadIdx.x, ty = threadIdx.y;          // 32 x 8
  #pragma unroll
  for (int i = 0; i < 32; i += 8)
    tile[ty + i][tx] = in[(size_t)(rowOff + k0 + ty + i) * inStride + colOff + n0 + tx];
  __syncthreads();
  #pragma unroll
  for (int i = 0; i < 32; i += 8)
    out[(size_t)(n0 + ty + i) * outStride + k0 + tx] = __float2bfloat16(tile[tx][ty + i]);
}

// ---------------- layernorm: f32 in -> bf16 out ----------------
__global__ __launch_bounds__(256) void ln_kernel(const float* __restrict__ x, const float* __restrict__ w,
                                                 const float* __restrict__ b, bf16* __restrict__ out) {
  int row = blockIdx.x, t = threadIdx.x;
  const float* xr = x + (size_t)row * DIM;
  float4 xv = *(const float4*)(xr + t * 4);
  float s  = xv.x + xv.y + xv.z + xv.w;
  float s2 = xv.x * xv.x + xv.y * xv.y + xv.z * xv.z + xv.w * xv.w;
  #pragma unroll
  for (int off = 32; off; off >>= 1) { s += __shfl_xor(s, off, 64); s2 += __shfl_xor(s2, off, 64); }
  __shared__ float sh_s[4], sh_s2[4], sh_mu, sh_rstd;
  int wid = t >> 6;
  if ((t & 63) == 0) { sh_s[wid] = s; sh_s2[wid] = s2; }
  __syncthreads();
  if (t == 0) {
    float S1 = sh_s[0] + sh_s[1] + sh_s[2] + sh_s[3];
    float S2 = sh_s2[0] + sh_s2[1] + sh_s2[2] + sh_s2[3];
    float mu = S1 * (1.0f / DIM);
    float var = S2 * (1.0f / DIM) - mu * mu;
    sh_mu = mu; sh_rstd = rsqrtf(var + 1e-5f);
  }
  __syncthreads();
  float mu = sh_mu, rstd = sh_rstd;
  float4 wv = *(const float4*)(w + t * 4);
  float4 bv = *(const float4*)(b + t * 4);
  bf16* orow = out + (size_t)row * DIM + t * 4;
  orow[0] = __float2bfloat16((xv.x - mu) * rstd * wv.x + bv.x);
  orow[1] = __float2bfloat16((xv.y - mu) * rstd * wv.y + bv.y);
  orow[2] = __float2bfloat16((xv.z - mu) * rstd * wv.z + bv.z);
  orow[3] = __float2bfloat16((xv.w - mu) * rstd * wv.w + bv.w);
}

// ---------------- GEMM 128x128 (m97 structure): C = A(M,K) x Bt(N,K)^T ----------------
#define MODE_PLAIN 0
#define MODE_GELU  1
#define MODE_RES   2
#define BM 128
#define BN 128
#define BK 32

__global__ __launch_bounds__(256) void gemm128_kernel(const bf16* __restrict__ A, const bf16* __restrict__ Bt,
                                                      const float* __restrict__ bias, bf16* __restrict__ outb,
                                                      float* __restrict__ resf, int N, int K, int mode) {
  __shared__ __align__(16) bf16 As[BM * BK];   // 8 KB, row-major [m][k], unpadded (DMA layout)
  __shared__ __align__(16) bf16 Bs[BN * BK];   // 8 KB, row-major [n][k]
  int t = threadIdx.x;
  int w = t >> 6, l = t & 63;
  int l15 = l & 15, quad = l >> 4;
  int col0 = blockIdx.x * BN, row0 = blockIdx.y * BM;
  int wm = (w >> 1) * 64, wn = (w & 1) * 64;   // wave quadrant

  f32x4 acc[4][4] = {};

  // staging: lane l of wave w loads 8 elems at tile element offset w*512 + l*8
  // -> row sm = w*16 + (l>>2), col sk = (l&3)*8 ; round 1 adds 64 rows (+2048 elems)
  int sm = w * 16 + (l >> 2);
  int sk = (l & 3) * 8;
  const bf16* ag0 = A  + (size_t)(row0 + sm) * K + sk;
  const bf16* ag1 = A  + (size_t)(row0 + 64 + sm) * K + sk;
  const bf16* bg0 = Bt + (size_t)(col0 + sm) * K + sk;
  const bf16* bg1 = Bt + (size_t)(col0 + 64 + sm) * K + sk;
  bf16* lA0 = As + w * 512;          // wave-uniform LDS bases
  bf16* lA1 = As + 2048 + w * 512;
  bf16* lB0 = Bs + w * 512;
  bf16* lB1 = Bs + 2048 + w * 512;

  for (int k0 = 0; k0 < K; k0 += BK) {
    gload_lds16(ag0 + k0, lA0);
    gload_lds16(ag1 + k0, lA1);
    gload_lds16(bg0 + k0, lB0);
    gload_lds16(bg1 + k0, lB1);
    __syncthreads();
    bf16x8 af[4], bfr[4];
    #pragma unroll
    for (int i = 0; i < 4; ++i) af[i]  = *(const bf16x8*)&As[(wm + i * 16 + l15) * BK + quad * 8];
    #pragma unroll
    for (int j = 0; j < 4; ++j) bfr[j] = *(const bf16x8*)&Bs[(wn + j * 16 + l15) * BK + quad * 8];
    #pragma unroll
    for (int i = 0; i < 4; ++i)
      #pragma unroll
      for (int j = 0; j < 4; ++j)
        acc[i][j] = __builtin_amdgcn_mfma_f32_16x16x32_bf16(af[i], bfr[j], acc[i][j], 0, 0, 0);
    __syncthreads();
  }

  // epilogue: row = row0+wm+i*16+quad*4+r, col = col0+wn+j*16+l15
  #pragma unroll
  for (int i = 0; i < 4; ++i) {
    #pragma unroll
    for (int j = 0; j < 4; ++j) {
      int gcol = col0 + wn + j * 16 + l15;
      float bval = (mode != MODE_PLAIN && bias != nullptr) ? bias[gcol] : 0.0f;
      #pragma unroll
      for (int r = 0; r < 4; ++r) {
        int grow = row0 + wm + i * 16 + quad * 4 + r;
        float val = acc[i][j][r];
        size_t idx = (size_t)grow * N + gcol;
        if (mode == MODE_RES) {
          resf[idx] = resf[idx] + val + bval;
        } else {
          if (mode == MODE_GELU) {
            float u = val + bval;
            val = 0.5f * u * (1.0f + erff(u * 0.70710678118654752f));
          }
          outb[idx] = __float2bfloat16(val);
        }
      }
    }
  }
}

// ---------------- MFMA flash attention (unchanged from round 4) ----------------
#define ALDP 72

__global__ __launch_bounds__(256) void attn_mfma_kernel(const bf16* __restrict__ q, const bf16* __restrict__ k,
                                                        const bf16* __restrict__ v, bf16* __restrict__ o) {
  __shared__ __align__(16) short Kl[64][ALDP];
  __shared__ __align__(16) short Vt[64][ALDP];
  __shared__ __align__(16) short Pl[64][ALDP];

  int t = threadIdx.x;
  int lane = t & 63, w = t >> 6;
  int l15 = lane & 15, quad = lane >> 4;
  int qt = blockIdx.x;
  int bh = blockIdx.y;
  int b = bh >> 4, hh = bh & 15;

  bf16x8 qfrag[2];
  {
    const bf16* qp = q + (size_t)(b * NN + qt * 64 + w * 16 + l15) * DIM + hh * DHEAD + quad * 8;
    #pragma unroll
    for (int ks = 0; ks < 2; ++ks) {
      bf16x8 raw = *(const bf16x8*)(qp + ks * 32);
      bf16x8 sc;
      #pragma unroll
      for (int e = 0; e < 8; ++e) sc[e] = bfbits(bitsbf(raw[e]) * 0.03125f);
      qfrag[ks] = sc;
    }
  }

  f32x4 Oacc[4] = {{}, {}, {}, {}};
  float mrow[4] = {-1e30f, -1e30f, -1e30f, -1e30f};
  float lrow[4] = {0.f, 0.f, 0.f, 0.f};

  int srow = t >> 2, sc0 = (t & 3) * 16;

  for (int kt = 0; kt < MMK / 64; ++kt) {
    __syncthreads();
    {
      const bf16* kp = k + (size_t)(b * MMK + kt * 64 + srow) * DIM + hh * DHEAD + sc0;
      *(bf16x8*)&Kl[srow][sc0]     = *(const bf16x8*)kp;
      *(bf16x8*)&Kl[srow][sc0 + 8] = *(const bf16x8*)(kp + 8);
      const bf16* vp = v + (size_t)(b * MMK + kt * 64 + srow) * DIM + hh * DHEAD + sc0;
      bf16x8 v0 = *(const bf16x8*)vp;
      bf16x8 v1 = *(const bf16x8*)(vp + 8);
      #pragma unroll
      for (int e = 0; e < 8; ++e) {
        Vt[sc0 + e][srow]     = v0[e];
        Vt[sc0 + 8 + e][srow] = v1[e];
      }
    }
    __syncthreads();

    f32x4 S[4] = {{}, {}, {}, {}};
    #pragma unroll
    for (int ks = 0; ks < 2; ++ks) {
      #pragma unroll
      for (int j = 0; j < 4; ++j) {
        bf16x8 bfr = *(const bf16x8*)&Kl[j * 16 + l15][ks * 32 + quad * 8];
        S[j] = __builtin_amdgcn_mfma_f32_16x16x32_bf16(qfrag[ks], bfr, S[j], 0, 0, 0);
      }
    }

    #pragma unroll
    for (int r = 0; r < 4; ++r) {
      float tm = fmaxf(fmaxf(S[0][r], S[1][r]), fmaxf(S[2][r], S[3][r]));
      tm = fmaxf(tm, __shfl_xor(tm, 1, 64));
      tm = fmaxf(tm, __shfl_xor(tm, 2, 64));
      tm = fmaxf(tm, __shfl_xor(tm, 4, 64));
      tm = fmaxf(tm, __shfl_xor(tm, 8, 64));
      float mn = fmaxf(mrow[r], tm);
      float alpha = __expf(mrow[r] - mn);
      mrow[r] = mn;
      float rs = 0.f;
      #pragma unroll
      for (int j = 0; j < 4; ++j) {
        float p = __expf(S[j][r] - mn);
        S[j][r] = p;
        rs += p;
      }
      rs += __shfl_xor(rs, 1, 64);
      rs += __shfl_xor(rs, 2, 64);
      rs += __shfl_xor(rs, 4, 64);
      rs += __shfl_xor(rs, 8, 64);
      lrow[r] = lrow[r] * alpha + rs;
      #pragma unroll
      for (int j = 0; j < 4; ++j) {
        Oacc[j][r] *= alpha;
        Pl[w * 16 + quad * 4 + r][j * 16 + l15] = bfbits(S[j][r]);
      }
    }
    __syncthreads();

    #pragma unroll
    for (int ks = 0; ks < 2; ++ks) {
      bf16x8 pa = *(const bf16x8*)&Pl[w * 16 + l15][ks * 32 + quad * 8];
      #pragma unroll
      for (int j = 0; j < 4; ++j) {
        bf16x8 vb = *(const bf16x8*)&Vt[j * 16 + l15][ks * 32 + quad * 8];
        Oacc[j] = __builtin_amdgcn_mfma_f32_16x16x32_bf16(pa, vb, Oacc[j], 0, 0, 0);
      }
    }
  }

  #pragma unroll
  for (int r = 0; r < 4; ++r) {
    float inv = 1.0f / lrow[r];
    bf16* op = o + (size_t)(b * NN + qt * 64 + w * 16 + quad * 4 + r) * DIM + hh * DHEAD;
    #pragma unroll
    for (int j = 0; j < 4; ++j)
      op[j * 16 + l15] = __float2bfloat16(Oacc[j][r] * inv);
  }
}

// ---------------- host orchestration ----------------
extern "C" void kernel_launch(void* const* d_in, const int* in_sizes, int n_in,
                              void* d_out, int out_size, void* d_ws, size_t ws_size,
                              hipStream_t stream) {
  const float* x_in = (const float*)d_in[0];
  const float* m    = (const float*)d_in[1];
  const float* Wq   = (const float*)d_in[2];
  const float* Wk   = (const float*)d_in[3];
  const float* Wv   = (const float*)d_in[4];
  const float* Wo   = (const float*)d_in[5];
  const float* bo   = (const float*)d_in[6];
  const float* ln1w = (const float*)d_in[7];
  const float* ln1b = (const float*)d_in[8];
  const float* W1   = (const float*)d_in[9];
  const float* b1   = (const float*)d_in[10];
  const float* W2   = (const float*)d_in[11];
  const float* b2   = (const float*)d_in[12];
  const float* ln2w = (const float*)d_in[13];
  const float* ln2b = (const float*)d_in[14];

  float* xf = (float*)d_out;   // fp32 residual in d_out

  char* ws = (char*)d_ws;
  bf16* h   = (bf16*)(ws + 0);
  bf16* mb  = (bf16*)(ws + (8u  << 20));
  bf16* qb  = (bf16*)(ws + (16u << 20));
  bf16* kb  = (bf16*)(ws + (24u << 20));
  bf16* vb  = (bf16*)(ws + (32u << 20));
  bf16* ffh = (bf16*)(ws + (16u << 20));
  bf16* wt  = (bf16*)(ws + (40u << 20));

  const int NTOK = ROWS * DIM;

  hipMemcpyAsync(xf, x_in, (size_t)NTOK * sizeof(float), hipMemcpyDeviceToDevice, stream);
  f2b_kernel<<<dim3((NTOK + 255) / 256), dim3(256), 0, stream>>>(m, mb, NTOK);

  dim3 blk(256);
  dim3 tblk(32, 8);
  dim3 gemm_n1(DIM / BN, ROWS / BM);     // (8, 32)
  dim3 gemm_n2(2048 / BN, ROWS / BM);    // (16, 32)
  dim3 tr_1k(DIM / 32, DIM / 32);
  dim3 tr_w1(2048 / 32, DIM / 32);
  dim3 tr_w2(DIM / 32, 2048 / 32);
  dim3 attn_grid(NN / 64, BB * HEADS);

  for (int L = 0; L < DEPTH; ++L) {
    const float* WqL = Wq + (size_t)L * DIM * DIM;
    const float* WkL = Wk + (size_t)L * DIM * DIM;
    const float* WvL = Wv + (size_t)L * DIM * DIM;
    const float* WoL = Wo + (size_t)L * DIM * DIM;
    const float* W1L = W1 + (size_t)L * DIM * MLPD;
    const float* W2L = W2 + (size_t)L * MLPD * DIM;

    // --- cross-attention block ---
    ln_kernel<<<dim3(ROWS), blk, 0, stream>>>(xf, ln1w + L * DIM, ln1b + L * DIM, h);

    transpose_f2b<<<tr_1k, tblk, 0, stream>>>(WqL, wt, DIM, 0, 0, DIM);
    gemm128_kernel<<<gemm_n1, blk, 0, stream>>>(h, wt, nullptr, qb, nullptr, DIM, DIM, MODE_PLAIN);
    transpose_f2b<<<tr_1k, tblk, 0, stream>>>(WkL, wt, DIM, 0, 0, DIM);
    gemm128_kernel<<<gemm_n1, blk, 0, stream>>>(mb, wt, nullptr, kb, nullptr, DIM, DIM, MODE_PLAIN);
    transpose_f2b<<<tr_1k, tblk, 0, stream>>>(WvL, wt, DIM, 0, 0, DIM);
    gemm128_kernel<<<gemm_n1, blk, 0, stream>>>(mb, wt, nullptr, vb, nullptr, DIM, DIM, MODE_PLAIN);

    attn_mfma_kernel<<<attn_grid, blk, 0, stream>>>(qb, kb, vb, h);

    transpose_f2b<<<tr_1k, tblk, 0, stream>>>(WoL, wt, DIM, 0, 0, DIM);
    gemm128_kernel<<<gemm_n1, blk, 0, stream>>>(h, wt, bo + L * DIM, nullptr, xf, DIM, DIM, MODE_RES);

    // --- MLP block ---
    ln_kernel<<<dim3(ROWS), blk, 0, stream>>>(xf, ln2w + L * DIM, ln2b + L * DIM, h);

    for (int half = 0; half < 2; ++half) {
      transpose_f2b<<<tr_w1, tblk, 0, stream>>>(W1L, wt, MLPD, 0, half * 2048, DIM);
      gemm128_kernel<<<gemm_n2, blk, 0, stream>>>(h, wt, b1 + (size_t)L * MLPD + half * 2048, ffh, nullptr,
                                                  2048, DIM, MODE_GELU);
      transpose_f2b<<<tr_w2, tblk, 0, stream>>>(W2L, wt, DIM, half * 2048, 0, 2048);
      gemm128_kernel<<<gemm_n1, blk, 0, stream>>>(ffh, wt, (half == 0) ? (b2 + (size_t)L * DIM) : nullptr,
                                                  nullptr, xf, DIM, 2048, MODE_RES);
    }
  }
}

// Round 6
// 1786.340 us; speedup vs baseline: 1.1763x; 1.1763x over previous
//
#include <hip/hip_runtime.h>
#include <hip/hip_bf16.h>
#include <math.h>

typedef __hip_bfloat16 bf16;
typedef __attribute__((ext_vector_type(8))) short bf16x8;
typedef __attribute__((ext_vector_type(4))) float f32x4;

#define DEPTH  4
#define HEADS  16
#define DIM    1024
#define DHEAD  64
#define MLPD   4096
#define BB     4
#define NN     1024
#define MMK    1024
#define ROWS   (BB*NN)     // 4096 token rows
#define QKVS   3072        // packed qkv row stride

__device__ inline float bitsbf(short s) {
  union { float f; unsigned u; } c; c.u = ((unsigned)(unsigned short)s) << 16; return c.f;
}
__device__ inline short bfbits(float f) {
  bf16 h = __float2bfloat16(f); return *(short*)&h;
}

// async global->LDS 16B per lane. LDS dest = wave-uniform base + lane*16B.
__device__ inline void gload_lds16(const bf16* g, bf16* l) {
  __builtin_amdgcn_global_load_lds((const __attribute__((address_space(1))) unsigned int*)g,
                                   (__attribute__((address_space(3))) unsigned int*)l, 16, 0, 0);
}

// ---------------- f32 -> bf16 convert ----------------
__global__ __launch_bounds__(256) void f2b_kernel(const float* __restrict__ in, bf16* __restrict__ out, int n) {
  int i = blockIdx.x * 256 + threadIdx.x;
  if (i < n) out[i] = __float2bfloat16(in[i]);
}

// ---------------- generalized transpose + f32->bf16 ----------------
// out[n][k] = bf16( in[(rowOff + k) * inStride + colOff + n] )
__global__ __launch_bounds__(256) void transpose_f2b(const float* __restrict__ in, bf16* __restrict__ out,
                                                     int inStride, int rowOff, int colOff, int outStride) {
  __shared__ float tile[32][33];
  int n0 = blockIdx.x * 32, k0 = blockIdx.y * 32;
  int tx = threadIdx.x, ty = threadIdx.y;          // 32 x 8
  #pragma unroll
  for (int i = 0; i < 32; i += 8)
    tile[ty + i][tx] = in[(size_t)(rowOff + k0 + ty + i) * inStride + colOff + n0 + tx];
  __syncthreads();
  #pragma unroll
  for (int i = 0; i < 32; i += 8)
    out[(size_t)(n0 + ty + i) * outStride + k0 + tx] = __float2bfloat16(tile[tx][ty + i]);
}

// ---------------- layernorm: f32 in -> bf16 out ----------------
__global__ __launch_bounds__(256) void ln_kernel(const float* __restrict__ x, const float* __restrict__ w,
                                                 const float* __restrict__ b, bf16* __restrict__ out) {
  int row = blockIdx.x, t = threadIdx.x;
  const float* xr = x + (size_t)row * DIM;
  float4 xv = *(const float4*)(xr + t * 4);
  float s  = xv.x + xv.y + xv.z + xv.w;
  float s2 = xv.x * xv.x + xv.y * xv.y + xv.z * xv.z + xv.w * xv.w;
  #pragma unroll
  for (int off = 32; off; off >>= 1) { s += __shfl_xor(s, off, 64); s2 += __shfl_xor(s2, off, 64); }
  __shared__ float sh_s[4], sh_s2[4], sh_mu, sh_rstd;
  int wid = t >> 6;
  if ((t & 63) == 0) { sh_s[wid] = s; sh_s2[wid] = s2; }
  __syncthreads();
  if (t == 0) {
    float S1 = sh_s[0] + sh_s[1] + sh_s[2] + sh_s[3];
    float S2 = sh_s2[0] + sh_s2[1] + sh_s2[2] + sh_s2[3];
    float mu = S1 * (1.0f / DIM);
    float var = S2 * (1.0f / DIM) - mu * mu;
    sh_mu = mu; sh_rstd = rsqrtf(var + 1e-5f);
  }
  __syncthreads();
  float mu = sh_mu, rstd = sh_rstd;
  float4 wv = *(const float4*)(w + t * 4);
  float4 bv = *(const float4*)(b + t * 4);
  bf16* orow = out + (size_t)row * DIM + t * 4;
  orow[0] = __float2bfloat16((xv.x - mu) * rstd * wv.x + bv.x);
  orow[1] = __float2bfloat16((xv.y - mu) * rstd * wv.y + bv.y);
  orow[2] = __float2bfloat16((xv.z - mu) * rstd * wv.z + bv.z);
  orow[3] = __float2bfloat16((xv.w - mu) * rstd * wv.w + bv.w);
}

// ---------------- GEMM BM=128 x BN=(JT*32): C = A(M,K) x Bt(N,K)^T ----------------
// JT=4 -> 128x128 tile (m97 structure); JT=2 -> 128x64 tile (for N=1024 GEMMs: 512 blocks).
// outb/resf indexed with outStride.
#define MODE_PLAIN 0
#define MODE_GELU  1
#define MODE_RES   2
#define BM 128
#define BK 32

template<int JT>
__global__ __launch_bounds__(256) void gemm_tile(const bf16* __restrict__ A, const bf16* __restrict__ Bt,
                                                 const float* __restrict__ bias, bf16* __restrict__ outb,
                                                 float* __restrict__ resf, int outStride, int K, int mode) {
  constexpr int BN = JT * 32;
  __shared__ __align__(16) bf16 As[BM * BK];   // 8 KB row-major [m][k], unpadded (DMA layout)
  __shared__ __align__(16) bf16 Bs[BN * BK];   // 8 or 4 KB row-major [n][k]
  int t = threadIdx.x;
  int w = t >> 6, l = t & 63;
  int l15 = l & 15, quad = l >> 4;
  int col0 = blockIdx.x * BN, row0 = blockIdx.y * BM;
  int wm = (w >> 1) * 64, wn = (w & 1) * (JT * 16);

  f32x4 acc[4][JT] = {};

  // staging: lane l of wave w loads 8 elems at tile element offset w*512 + l*8
  int sm = w * 16 + (l >> 2);
  int sk = (l & 3) * 8;
  const bf16* ag0 = A  + (size_t)(row0 + sm) * K + sk;
  const bf16* ag1 = A  + (size_t)(row0 + 64 + sm) * K + sk;
  const bf16* bg0 = Bt + (size_t)(col0 + sm) * K + sk;
  const bf16* bg1 = Bt + (size_t)(col0 + 64 + sm) * K + sk;   // used only when BN==128
  bf16* lA0 = As + w * 512;
  bf16* lA1 = As + 2048 + w * 512;
  bf16* lB0 = Bs + w * 512;
  bf16* lB1 = Bs + 2048 + w * 512;

  for (int k0 = 0; k0 < K; k0 += BK) {
    gload_lds16(ag0 + k0, lA0);
    gload_lds16(ag1 + k0, lA1);
    gload_lds16(bg0 + k0, lB0);
    if constexpr (JT == 4) gload_lds16(bg1 + k0, lB1);
    __syncthreads();
    bf16x8 af[4], bfr[JT];
    #pragma unroll
    for (int i = 0; i < 4; ++i)  af[i]  = *(const bf16x8*)&As[(wm + i * 16 + l15) * BK + quad * 8];
    #pragma unroll
    for (int j = 0; j < JT; ++j) bfr[j] = *(const bf16x8*)&Bs[(wn + j * 16 + l15) * BK + quad * 8];
    #pragma unroll
    for (int i = 0; i < 4; ++i)
      #pragma unroll
      for (int j = 0; j < JT; ++j)
        acc[i][j] = __builtin_amdgcn_mfma_f32_16x16x32_bf16(af[i], bfr[j], acc[i][j], 0, 0, 0);
    __syncthreads();
  }

  // epilogue: row = row0+wm+i*16+quad*4+r, col = col0+wn+j*16+l15
  #pragma unroll
  for (int i = 0; i < 4; ++i) {
    #pragma unroll
    for (int j = 0; j < JT; ++j) {
      int gcol = col0 + wn + j * 16 + l15;
      float bval = (mode != MODE_PLAIN && bias != nullptr) ? bias[gcol] : 0.0f;
      #pragma unroll
      for (int r = 0; r < 4; ++r) {
        int grow = row0 + wm + i * 16 + quad * 4 + r;
        float val = acc[i][j][r];
        size_t idx = (size_t)grow * outStride + gcol;
        if (mode == MODE_RES) {
          resf[idx] = resf[idx] + val + bval;
        } else {
          if (mode == MODE_GELU) {
            float u = val + bval;
            val = 0.5f * u * (1.0f + erff(u * 0.70710678118654752f));
          }
          outb[idx] = __float2bfloat16(val);
        }
      }
    }
  }
}

// ---------------- MFMA flash attention (packed qkv, row stride QKVS) ----------------
#define ALDP 72

__global__ __launch_bounds__(256) void attn_mfma_kernel(const bf16* __restrict__ qkv, bf16* __restrict__ o) {
  __shared__ __align__(16) short Kl[64][ALDP];
  __shared__ __align__(16) short Vt[64][ALDP];
  __shared__ __align__(16) short Pl[64][ALDP];

  int t = threadIdx.x;
  int lane = t & 63, w = t >> 6;
  int l15 = lane & 15, quad = lane >> 4;
  int qt = blockIdx.x;
  int bh = blockIdx.y;
  int b = bh >> 4, hh = bh & 15;

  const bf16* q = qkv;
  const bf16* k = qkv + 1024;
  const bf16* v = qkv + 2048;

  bf16x8 qfrag[2];
  {
    const bf16* qp = q + (size_t)(b * NN + qt * 64 + w * 16 + l15) * QKVS + hh * DHEAD + quad * 8;
    #pragma unroll
    for (int ks = 0; ks < 2; ++ks) {
      bf16x8 raw = *(const bf16x8*)(qp + ks * 32);
      bf16x8 sc;
      #pragma unroll
      for (int e = 0; e < 8; ++e) sc[e] = bfbits(bitsbf(raw[e]) * 0.03125f);
      qfrag[ks] = sc;
    }
  }

  f32x4 Oacc[4] = {{}, {}, {}, {}};
  float mrow[4] = {-1e30f, -1e30f, -1e30f, -1e30f};
  float lrow[4] = {0.f, 0.f, 0.f, 0.f};

  int srow = t >> 2, sc0 = (t & 3) * 16;

  for (int kt = 0; kt < MMK / 64; ++kt) {
    __syncthreads();
    {
      const bf16* kp = k + (size_t)(b * MMK + kt * 64 + srow) * QKVS + hh * DHEAD + sc0;
      *(bf16x8*)&Kl[srow][sc0]     = *(const bf16x8*)kp;
      *(bf16x8*)&Kl[srow][sc0 + 8] = *(const bf16x8*)(kp + 8);
      const bf16* vp = v + (size_t)(b * MMK + kt * 64 + srow) * QKVS + hh * DHEAD + sc0;
      bf16x8 v0 = *(const bf16x8*)vp;
      bf16x8 v1 = *(const bf16x8*)(vp + 8);
      #pragma unroll
      for (int e = 0; e < 8; ++e) {
        Vt[sc0 + e][srow]     = v0[e];
        Vt[sc0 + 8 + e][srow] = v1[e];
      }
    }
    __syncthreads();

    f32x4 S[4] = {{}, {}, {}, {}};
    #pragma unroll
    for (int ks = 0; ks < 2; ++ks) {
      #pragma unroll
      for (int j = 0; j < 4; ++j) {
        bf16x8 bfr = *(const bf16x8*)&Kl[j * 16 + l15][ks * 32 + quad * 8];
        S[j] = __builtin_amdgcn_mfma_f32_16x16x32_bf16(qfrag[ks], bfr, S[j], 0, 0, 0);
      }
    }

    #pragma unroll
    for (int r = 0; r < 4; ++r) {
      float tm = fmaxf(fmaxf(S[0][r], S[1][r]), fmaxf(S[2][r], S[3][r]));
      tm = fmaxf(tm, __shfl_xor(tm, 1, 64));
      tm = fmaxf(tm, __shfl_xor(tm, 2, 64));
      tm = fmaxf(tm, __shfl_xor(tm, 4, 64));
      tm = fmaxf(tm, __shfl_xor(tm, 8, 64));
      float mn = fmaxf(mrow[r], tm);
      float alpha = __expf(mrow[r] - mn);
      mrow[r] = mn;
      float rs = 0.f;
      #pragma unroll
      for (int j = 0; j < 4; ++j) {
        float p = __expf(S[j][r] - mn);
        S[j][r] = p;
        rs += p;
      }
      rs += __shfl_xor(rs, 1, 64);
      rs += __shfl_xor(rs, 2, 64);
      rs += __shfl_xor(rs, 4, 64);
      rs += __shfl_xor(rs, 8, 64);
      lrow[r] = lrow[r] * alpha + rs;
      #pragma unroll
      for (int j = 0; j < 4; ++j) {
        Oacc[j][r] *= alpha;
        Pl[w * 16 + quad * 4 + r][j * 16 + l15] = bfbits(S[j][r]);
      }
    }
    __syncthreads();

    #pragma unroll
    for (int ks = 0; ks < 2; ++ks) {
      bf16x8 pa = *(const bf16x8*)&Pl[w * 16 + l15][ks * 32 + quad * 8];
      #pragma unroll
      for (int j = 0; j < 4; ++j) {
        bf16x8 vb = *(const bf16x8*)&Vt[j * 16 + l15][ks * 32 + quad * 8];
        Oacc[j] = __builtin_amdgcn_mfma_f32_16x16x32_bf16(pa, vb, Oacc[j], 0, 0, 0);
      }
    }
  }

  #pragma unroll
  for (int r = 0; r < 4; ++r) {
    float inv = 1.0f / lrow[r];
    bf16* op = o + (size_t)(b * NN + qt * 64 + w * 16 + quad * 4 + r) * DIM + hh * DHEAD;
    #pragma unroll
    for (int j = 0; j < 4; ++j)
      op[j * 16 + l15] = __float2bfloat16(Oacc[j][r] * inv);
  }
}

// ---------------- host orchestration ----------------
extern "C" void kernel_launch(void* const* d_in, const int* in_sizes, int n_in,
                              void* d_out, int out_size, void* d_ws, size_t ws_size,
                              hipStream_t stream) {
  const float* x_in = (const float*)d_in[0];
  const float* m    = (const float*)d_in[1];
  const float* Wq   = (const float*)d_in[2];
  const float* Wk   = (const float*)d_in[3];
  const float* Wv   = (const float*)d_in[4];
  const float* Wo   = (const float*)d_in[5];
  const float* bo   = (const float*)d_in[6];
  const float* ln1w = (const float*)d_in[7];
  const float* ln1b = (const float*)d_in[8];
  const float* W1   = (const float*)d_in[9];
  const float* b1   = (const float*)d_in[10];
  const float* W2   = (const float*)d_in[11];
  const float* b2   = (const float*)d_in[12];
  const float* ln2w = (const float*)d_in[13];
  const float* ln2b = (const float*)d_in[14];

  float* xf = (float*)d_out;   // fp32 residual in d_out

  char* ws = (char*)d_ws;
  // layout (44 MB): h [0,8), mb [8,16), qkv [16,40) packed (4096 x 3072 bf16),
  //                 wt [40,44). ffh (4096x2048) reuses [16,32) in MLP phase.
  bf16* h    = (bf16*)(ws + 0);
  bf16* mb   = (bf16*)(ws + (8u  << 20));
  bf16* qkv  = (bf16*)(ws + (16u << 20));
  bf16* ffh  = (bf16*)(ws + (16u << 20));
  bf16* wt   = (bf16*)(ws + (40u << 20));

  const int NTOK = ROWS * DIM;

  hipMemcpyAsync(xf, x_in, (size_t)NTOK * sizeof(float), hipMemcpyDeviceToDevice, stream);
  f2b_kernel<<<dim3((NTOK + 255) / 256), dim3(256), 0, stream>>>(m, mb, NTOK);

  dim3 blk(256);
  dim3 tblk(32, 8);
  dim3 g_n1(DIM / 64, ROWS / BM);       // (16, 32) = 512 blocks, JT=2
  dim3 g_n2(2048 / 128, ROWS / BM);     // (16, 32) = 512 blocks, JT=4
  dim3 tr_1k(DIM / 32, DIM / 32);
  dim3 tr_w1(2048 / 32, DIM / 32);
  dim3 tr_w2(DIM / 32, 2048 / 32);
  dim3 attn_grid(NN / 64, BB * HEADS);

  for (int L = 0; L < DEPTH; ++L) {
    const float* WqL = Wq + (size_t)L * DIM * DIM;
    const float* WkL = Wk + (size_t)L * DIM * DIM;
    const float* WvL = Wv + (size_t)L * DIM * DIM;
    const float* WoL = Wo + (size_t)L * DIM * DIM;
    const float* W1L = W1 + (size_t)L * DIM * MLPD;
    const float* W2L = W2 + (size_t)L * MLPD * DIM;

    // --- cross-attention block ---
    ln_kernel<<<dim3(ROWS), blk, 0, stream>>>(xf, ln1w + L * DIM, ln1b + L * DIM, h);

    // K|V fused: Bt = [Wk^T ; Wv^T] (2048 x 1024) in wt
    transpose_f2b<<<tr_1k, tblk, 0, stream>>>(WkL, wt, DIM, 0, 0, DIM);
    transpose_f2b<<<tr_1k, tblk, 0, stream>>>(WvL, wt + 1024 * 1024, DIM, 0, 0, DIM);
    gemm_tile<4><<<g_n2, blk, 0, stream>>>(mb, wt, nullptr, qkv + 1024, nullptr, QKVS, DIM, MODE_PLAIN);

    transpose_f2b<<<tr_1k, tblk, 0, stream>>>(WqL, wt, DIM, 0, 0, DIM);
    gemm_tile<2><<<g_n1, blk, 0, stream>>>(h, wt, nullptr, qkv, nullptr, QKVS, DIM, MODE_PLAIN);

    attn_mfma_kernel<<<attn_grid, blk, 0, stream>>>(qkv, h);

    transpose_f2b<<<tr_1k, tblk, 0, stream>>>(WoL, wt, DIM, 0, 0, DIM);
    gemm_tile<2><<<g_n1, blk, 0, stream>>>(h, wt, bo + L * DIM, nullptr, xf, DIM, DIM, MODE_RES);

    // --- MLP block (two N=2048 halves; ffh reuses qkv space) ---
    ln_kernel<<<dim3(ROWS), blk, 0, stream>>>(xf, ln2w + L * DIM, ln2b + L * DIM, h);

    for (int half = 0; half < 2; ++half) {
      transpose_f2b<<<tr_w1, tblk, 0, stream>>>(W1L, wt, MLPD, 0, half * 2048, DIM);
      gemm_tile<4><<<g_n2, blk, 0, stream>>>(h, wt, b1 + (size_t)L * MLPD + half * 2048, ffh, nullptr,
                                             2048, DIM, MODE_GELU);
      transpose_f2b<<<tr_w2, tblk, 0, stream>>>(W2L, wt, DIM, half * 2048, 0, 2048);
      gemm_tile<2><<<g_n1, blk, 0, stream>>>(ffh, wt, (half == 0) ? (b2 + (size_t)L * DIM) : nullptr,
                                             nullptr, xf, DIM, 2048, MODE_RES);
    }
  }
}